// Round 1
// baseline (484.983 us; speedup 1.0000x reference)
//
#include <hip/hip_runtime.h>
#include <hip/hip_bf16.h>

// SDNN: xw1 = x@w1[:, :1024]+b1 ; h[:,j]=relu(xw1[:,j]+h@w2[:,j]) j<1024 ;
//       out = h@w3[:1024]+x@w4+b2.  Rows of the recurrence are independent ->
//       per-WG blocked scan (cross-block MFMA + in-block rank-1 updates).

typedef __bf16 bf16x8 __attribute__((ext_vector_type(8)));
typedef float f32x4 __attribute__((ext_vector_type(4)));
typedef int i32x4 __attribute__((ext_vector_type(4)));

__device__ __forceinline__ void gload_lds16(const void* gsrc, void* ldst) {
#if __has_builtin(__builtin_amdgcn_global_load_lds)
  void* g = const_cast<void*>(gsrc);
  __builtin_amdgcn_global_load_lds((__attribute__((address_space(1))) void*)g,
                                   (__attribute__((address_space(3))) void*)ldst,
                                   16, 0, 0);
#else
  *(i32x4*)ldst = *(const i32x4*)gsrc;
#endif
}

// ---------- converts ----------
__global__ __launch_bounds__(256) void cvt_bf16x8(const float* __restrict__ src,
                                                  __hip_bfloat16* __restrict__ dst,
                                                  long n) {
  long i = ((long)blockIdx.x * blockDim.x + threadIdx.x) * 8;
  if (i >= n) return;
  f32x4 a = *(const f32x4*)(src + i);
  f32x4 b = *(const f32x4*)(src + i + 4);
  union { __hip_bfloat16 h[8]; i32x4 v; } u;
#pragma unroll
  for (int j = 0; j < 4; ++j) {
    u.h[j]     = __float2bfloat16(a[j]);
    u.h[4 + j] = __float2bfloat16(b[j]);
  }
  *(i32x4*)(dst + i) = u.v;
}

// dst[j][k] = (j < Juse) ? bf16(src[k][j]) : 0 ; dst is [1024][Kuse]
__global__ __launch_bounds__(256) void transpose_cvt(const float* __restrict__ src,
                                                     __hip_bfloat16* __restrict__ dst,
                                                     int srcStride, int Kuse, int Juse) {
  __shared__ float tile[32][33];
  const int k0 = blockIdx.x * 32, j0 = blockIdx.y * 32;
  const int tx = threadIdx.x, ty = threadIdx.y;  // 32 x 8
#pragma unroll
  for (int i = 0; i < 4; ++i) {
    const int k = k0 + ty + i * 8, j = j0 + tx;
    tile[ty + i * 8][tx] = (j < Juse) ? src[(size_t)k * srcStride + j] : 0.f;
  }
  __syncthreads();
#pragma unroll
  for (int i = 0; i < 4; ++i) {
    const int j = j0 + ty + i * 8, k = k0 + tx;
    dst[(size_t)j * Kuse + k] = __float2bfloat16(tile[tx][ty + i * 8]);
  }
}

// ---------- bf16 MFMA GEMM, C = sum_p A_p @ B_p^T + bias (m97 structure) ----------
// A: [M][K] bf16 row-major ; Bt: [N][K] bf16 row-major ; C: [M][Cstride] f32
template <int NP>
__global__ __launch_bounds__(256) void gemm_bf16_nt(
    const __hip_bfloat16* __restrict__ A0, const __hip_bfloat16* __restrict__ B0t, int K0,
    const __hip_bfloat16* __restrict__ A1, const __hip_bfloat16* __restrict__ B1t, int K1,
    const float* __restrict__ bias, float* __restrict__ C, int Cstride, int Nvalid) {
  __shared__ __align__(16) __hip_bfloat16 As[128 * 64];
  __shared__ __align__(16) __hip_bfloat16 Bs[128 * 64];
  const int tid = threadIdx.x;
  const int l = tid & 63;
  const int w = tid >> 6;
  const int wr = w >> 1, wc = w & 1;
  const int bm = blockIdx.x * 128;
  const int bn = blockIdx.y * 128;

  f32x4 acc[4][4] = {};

#pragma unroll
  for (int p = 0; p < NP; ++p) {
    const __hip_bfloat16* A  = (p == 0) ? A0 : A1;
    const __hip_bfloat16* Bt = (p == 0) ? B0t : B1t;
    const int K = (p == 0) ? K0 : K1;
    for (int kt = 0; kt < K; kt += 64) {
      __syncthreads();
      const int srow = tid >> 3;
      const int sk = (tid & 7) * 8;
#pragma unroll
      for (int i = 0; i < 4; ++i) {
        gload_lds16(A  + (size_t)(bm + i * 32 + srow) * K + kt + sk,
                    &As[(i * 32 + srow) * 64 + sk]);
        gload_lds16(Bt + (size_t)(bn + i * 32 + srow) * K + kt + sk,
                    &Bs[(i * 32 + srow) * 64 + sk]);
      }
      __syncthreads();
#pragma unroll
      for (int kk = 0; kk < 64; kk += 32) {
        const int ko = kk + (l >> 4) * 8;
        bf16x8 aq[4], bq[4];
#pragma unroll
        for (int m = 0; m < 4; ++m)
          aq[m] = *(const bf16x8*)&As[(wr * 64 + m * 16 + (l & 15)) * 64 + ko];
#pragma unroll
        for (int n = 0; n < 4; ++n)
          bq[n] = *(const bf16x8*)&Bs[(wc * 64 + n * 16 + (l & 15)) * 64 + ko];
#pragma unroll
        for (int m = 0; m < 4; ++m)
#pragma unroll
          for (int n = 0; n < 4; ++n)
            acc[m][n] = __builtin_amdgcn_mfma_f32_16x16x32_bf16(aq[m], bq[n], acc[m][n], 0, 0, 0);
      }
    }
  }
#pragma unroll
  for (int m = 0; m < 4; ++m) {
    const int row0 = bm + wr * 64 + m * 16 + (l >> 4) * 4;
#pragma unroll
    for (int n = 0; n < 4; ++n) {
      const int col = bn + wc * 64 + n * 16 + (l & 15);
      if (col < Nvalid) {
        const float bv = bias[col];
#pragma unroll
        for (int j = 0; j < 4; ++j)
          C[(size_t)(row0 + j) * Cstride + col] = acc[m][n][j] + bv;
      }
    }
  }
}

// ---------- recurrence ----------
// Per WG: 32 rows, all 1024 steps in 16 blocks of 64 cols.
// H LDS layout (bf16): elem (r,k) at r*1024 + (((k>>3)^(r&7))<<3) + (k&7)  [XOR swizzle]
__global__ __launch_bounds__(256) void recurrence_k(
    const float* __restrict__ xw1,            // [8192][1024]
    const float* __restrict__ w2,             // [2048][2048] f32
    const __hip_bfloat16* __restrict__ w2t,   // [1024][1024] bf16, [j][k] = w2[k][j]
    __hip_bfloat16* __restrict__ hidden) {    // [8192][1024]
  __shared__ __align__(16) __hip_bfloat16 H[32 * 1024];
  __shared__ __align__(16) float accL[64 * 32];   // [c][r]
  __shared__ __align__(16) float w2blk[64 * 64];  // [jj][c] f32
  const int tid = threadIdx.x;
  const int l = tid & 63;
  const int w = tid >> 6;
  const int R0 = blockIdx.x * 32;
  const int rA = tid >> 3;  // in-block row (0..31)
  const int g  = tid & 7;   // in-block col group (8 cols each)

  for (int b = 0; b < 16; ++b) {
    const int B0 = b * 64;
    // phase 1a: stage in-block w2 [64][64] f32 via global_load_lds (linear)
#pragma unroll
    for (int i = 0; i < 4; ++i) {
      const int e = i * 1024 + tid * 4;
      const int jj = e >> 6, c = e & 63;
      gload_lds16(w2 + (size_t)(B0 + jj) * 2048 + (B0 + c), &w2blk[e]);
    }
    // phase 1b: init C frags from xw1 (frag layout: row=(l>>4)*4+j, col=l&15)
    f32x4 cf[2];
    const int col = B0 + w * 16 + (l & 15);
#pragma unroll
    for (int mt = 0; mt < 2; ++mt)
#pragma unroll
      for (int j = 0; j < 4; ++j) {
        const int row = R0 + mt * 16 + (l >> 4) * 4 + j;
        cf[mt][j] = xw1[(size_t)row * 1024 + col];
      }
    // phase 2: cross-block MFMA over previous columns
    for (int k0 = 0; k0 < B0; k0 += 32) {
      const int kr = k0 + (l >> 4) * 8;
      bf16x8 aq[2];
#pragma unroll
      for (int mt = 0; mt < 2; ++mt) {
        const int row = mt * 16 + (l & 15);
        const int gsw = (kr >> 3) ^ (row & 7);
        aq[mt] = *(const bf16x8*)&H[row * 1024 + gsw * 8];
      }
      const bf16x8 bq = *(const bf16x8*)&w2t[(size_t)col * 1024 + kr];
#pragma unroll
      for (int mt = 0; mt < 2; ++mt)
        cf[mt] = __builtin_amdgcn_mfma_f32_16x16x32_bf16(aq[mt], bq, cf[mt], 0, 0, 0);
    }
    // phase 3: frags -> accL[c][r]
#pragma unroll
    for (int mt = 0; mt < 2; ++mt)
#pragma unroll
      for (int j = 0; j < 4; ++j)
        accL[(w * 16 + (l & 15)) * 32 + mt * 16 + (l >> 4) * 4 + j] = cf[mt][j];
    __syncthreads();  // accL + w2blk(vmcnt) ready
    // phase 4: in-block sequential solve (rank-1 updates, fully unrolled)
    float ac[8];
#pragma unroll
    for (int i = 0; i < 8; ++i) ac[i] = accL[(g * 8 + i) * 32 + rA];
#pragma unroll
    for (int jj = 0; jj < 64; ++jj) {
      float own = fmaxf(ac[jj & 7], 0.f);              // valid on owner lanes
      const float hv = __shfl(own, (l & 56) | (jj >> 3), 64);
      if (g == (jj >> 3)) {
        const int k = B0 + jj;
        H[rA * 1024 + (((k >> 3) ^ (rA & 7)) << 3) + (k & 7)] = __float2bfloat16(hv);
      }
      const f32x4* wrow = (const f32x4*)&w2blk[jj * 64 + g * 8];
      const f32x4 wa = wrow[0], wb = wrow[1];
#pragma unroll
      for (int i = 0; i < 8; ++i) {
        const float wv = (i < 4) ? wa[i] : wb[i - 4];
        ac[i] += hv * (((g << 3) + i > jj) ? wv : 0.f);
      }
    }
    __syncthreads();  // H block visible to all
    // phase 5: copy this block's H to global hidden (16B per thread)
    {
      const int cc0 = g * 8;
      const int kk = B0 + cc0;
      const int gsw = (kk >> 3) ^ (rA & 7);
      const i32x4 v = *(const i32x4*)&H[rA * 1024 + gsw * 8];
      *(i32x4*)&hidden[(size_t)(R0 + rA) * 1024 + kk] = v;
    }
  }
}

extern "C" void kernel_launch(void* const* d_in, const int* in_sizes, int n_in,
                              void* d_out, int out_size, void* d_ws, size_t ws_size,
                              hipStream_t stream) {
  const float* x  = (const float*)d_in[0];
  const float* w1 = (const float*)d_in[1];
  const float* w2 = (const float*)d_in[2];
  const float* w3 = (const float*)d_in[3];
  const float* w4 = (const float*)d_in[4];
  const float* b1 = (const float*)d_in[5];
  const float* b2 = (const float*)d_in[6];
  float* out = (float*)d_out;

  char* ws = (char*)d_ws;
  size_t off = 0;
  auto alloc = [&](size_t bytes) {
    char* p = ws + off;
    off += (bytes + 255) & ~(size_t)255;
    return p;
  };
  __hip_bfloat16* x_bf = (__hip_bfloat16*)alloc(8192ull * 2048 * 2);
  float*          xw1  = (float*)alloc(8192ull * 1024 * 4);
  __hip_bfloat16* hid  = (__hip_bfloat16*)alloc(8192ull * 1024 * 2);
  __hip_bfloat16* w1t  = (__hip_bfloat16*)alloc(1024ull * 2048 * 2);
  __hip_bfloat16* w2t  = (__hip_bfloat16*)alloc(1024ull * 1024 * 2);
  __hip_bfloat16* w3t  = (__hip_bfloat16*)alloc(1024ull * 1024 * 2);
  __hip_bfloat16* w4t  = (__hip_bfloat16*)alloc(1024ull * 2048 * 2);

  cvt_bf16x8<<<dim3(8192), dim3(256), 0, stream>>>(x, x_bf, 8192L * 2048);

  dim3 tb(32, 8);
  transpose_cvt<<<dim3(64, 32), tb, 0, stream>>>(w1, w1t, 2048, 2048, 1024);
  transpose_cvt<<<dim3(32, 32), tb, 0, stream>>>(w2, w2t, 2048, 1024, 1024);
  transpose_cvt<<<dim3(32, 32), tb, 0, stream>>>(w3, w3t, 1000, 1024, 1000);
  transpose_cvt<<<dim3(64, 32), tb, 0, stream>>>(w4, w4t, 1000, 2048, 1000);

  // xw1 = x @ w1[:, :1024] + b1
  gemm_bf16_nt<1><<<dim3(64, 8), dim3(256), 0, stream>>>(
      x_bf, w1t, 2048, (const __hip_bfloat16*)nullptr, (const __hip_bfloat16*)nullptr, 0,
      b1, xw1, 1024, 1024);

  recurrence_k<<<dim3(256), dim3(256), 0, stream>>>(xw1, w2, w2t, hid);

  // out = hidden @ w3[:1024] + x @ w4 + b2
  gemm_bf16_nt<2><<<dim3(64, 8), dim3(256), 0, stream>>>(
      hid, w3t, 1024, x_bf, w4t, 2048, b2, out, 1000, 1000);

  (void)in_sizes; (void)n_in; (void)out_size; (void)ws_size;
}

// Round 2
// 431.107 us; speedup vs baseline: 1.1250x; 1.1250x over previous
//
#include <hip/hip_runtime.h>
#include <hip/hip_bf16.h>

// SDNN: xw1 = x@w1[:, :1024]+b1 ; h[:,j]=relu(xw1[:,j]+h@w2[:,j]) j<1024 ;
//       out = h@w3[:1024]+x@w4+b2.  Rows of the recurrence are independent ->
//       per-WG blocked scan (cross-block MFMA + grouped in-block solve).
// R1->R2: recurrence restructured 32rows/256WG -> 16rows/512WG (2 WG/CU),
//         solve grouped by 4 cols (owner-local chain, 1 broadcast per 4),
//         accL row-major padded (bank-conflict fix), aq/bq 1-deep prefetch.

typedef __bf16 bf16x8 __attribute__((ext_vector_type(8)));
typedef float f32x4 __attribute__((ext_vector_type(4)));
typedef int i32x4 __attribute__((ext_vector_type(4)));

__device__ __forceinline__ void gload_lds16(const void* gsrc, void* ldst) {
#if __has_builtin(__builtin_amdgcn_global_load_lds)
  void* g = const_cast<void*>(gsrc);
  __builtin_amdgcn_global_load_lds((__attribute__((address_space(1))) void*)g,
                                   (__attribute__((address_space(3))) void*)ldst,
                                   16, 0, 0);
#else
  *(i32x4*)ldst = *(const i32x4*)gsrc;
#endif
}

// ---------- converts ----------
__global__ __launch_bounds__(256) void cvt_bf16x8(const float* __restrict__ src,
                                                  __hip_bfloat16* __restrict__ dst,
                                                  long n) {
  long i = ((long)blockIdx.x * blockDim.x + threadIdx.x) * 8;
  if (i >= n) return;
  f32x4 a = *(const f32x4*)(src + i);
  f32x4 b = *(const f32x4*)(src + i + 4);
  union { __hip_bfloat16 h[8]; i32x4 v; } u;
#pragma unroll
  for (int j = 0; j < 4; ++j) {
    u.h[j]     = __float2bfloat16(a[j]);
    u.h[4 + j] = __float2bfloat16(b[j]);
  }
  *(i32x4*)(dst + i) = u.v;
}

// dst[j][k] = (j < Juse) ? bf16(src[k][j]) : 0 ; dst is [1024][Kuse]
__global__ __launch_bounds__(256) void transpose_cvt(const float* __restrict__ src,
                                                     __hip_bfloat16* __restrict__ dst,
                                                     int srcStride, int Kuse, int Juse) {
  __shared__ float tile[32][33];
  const int k0 = blockIdx.x * 32, j0 = blockIdx.y * 32;
  const int tx = threadIdx.x, ty = threadIdx.y;  // 32 x 8
#pragma unroll
  for (int i = 0; i < 4; ++i) {
    const int k = k0 + ty + i * 8, j = j0 + tx;
    tile[ty + i * 8][tx] = (j < Juse) ? src[(size_t)k * srcStride + j] : 0.f;
  }
  __syncthreads();
#pragma unroll
  for (int i = 0; i < 4; ++i) {
    const int j = j0 + ty + i * 8, k = k0 + tx;
    dst[(size_t)j * Kuse + k] = __float2bfloat16(tile[tx][ty + i * 8]);
  }
}

// ---------- bf16 MFMA GEMM, C = sum_p A_p @ B_p^T + bias (m97 structure) ----------
// A: [M][K] bf16 row-major ; Bt: [N][K] bf16 row-major ; C: [M][Cstride] f32
template <int NP>
__global__ __launch_bounds__(256) void gemm_bf16_nt(
    const __hip_bfloat16* __restrict__ A0, const __hip_bfloat16* __restrict__ B0t, int K0,
    const __hip_bfloat16* __restrict__ A1, const __hip_bfloat16* __restrict__ B1t, int K1,
    const float* __restrict__ bias, float* __restrict__ C, int Cstride, int Nvalid) {
  __shared__ __align__(16) __hip_bfloat16 As[128 * 64];
  __shared__ __align__(16) __hip_bfloat16 Bs[128 * 64];
  const int tid = threadIdx.x;
  const int l = tid & 63;
  const int w = tid >> 6;
  const int wr = w >> 1, wc = w & 1;
  const int bm = blockIdx.x * 128;
  const int bn = blockIdx.y * 128;

  f32x4 acc[4][4] = {};

#pragma unroll
  for (int p = 0; p < NP; ++p) {
    const __hip_bfloat16* A  = (p == 0) ? A0 : A1;
    const __hip_bfloat16* Bt = (p == 0) ? B0t : B1t;
    const int K = (p == 0) ? K0 : K1;
    for (int kt = 0; kt < K; kt += 64) {
      __syncthreads();
      const int srow = tid >> 3;
      const int sk = (tid & 7) * 8;
#pragma unroll
      for (int i = 0; i < 4; ++i) {
        gload_lds16(A  + (size_t)(bm + i * 32 + srow) * K + kt + sk,
                    &As[(i * 32 + srow) * 64 + sk]);
        gload_lds16(Bt + (size_t)(bn + i * 32 + srow) * K + kt + sk,
                    &Bs[(i * 32 + srow) * 64 + sk]);
      }
      __syncthreads();
#pragma unroll
      for (int kk = 0; kk < 64; kk += 32) {
        const int ko = kk + (l >> 4) * 8;
        bf16x8 aq[4], bq[4];
#pragma unroll
        for (int m = 0; m < 4; ++m)
          aq[m] = *(const bf16x8*)&As[(wr * 64 + m * 16 + (l & 15)) * 64 + ko];
#pragma unroll
        for (int n = 0; n < 4; ++n)
          bq[n] = *(const bf16x8*)&Bs[(wc * 64 + n * 16 + (l & 15)) * 64 + ko];
#pragma unroll
        for (int m = 0; m < 4; ++m)
#pragma unroll
          for (int n = 0; n < 4; ++n)
            acc[m][n] = __builtin_amdgcn_mfma_f32_16x16x32_bf16(aq[m], bq[n], acc[m][n], 0, 0, 0);
      }
    }
  }
#pragma unroll
  for (int m = 0; m < 4; ++m) {
    const int row0 = bm + wr * 64 + m * 16 + (l >> 4) * 4;
#pragma unroll
    for (int n = 0; n < 4; ++n) {
      const int col = bn + wc * 64 + n * 16 + (l & 15);
      if (col < Nvalid) {
        const float bv = bias[col];
#pragma unroll
        for (int j = 0; j < 4; ++j)
          C[(size_t)(row0 + j) * Cstride + col] = acc[m][n][j] + bv;
      }
    }
  }
}

// ---------- recurrence (v2) ----------
// Per WG: 16 rows, all 1024 steps in 16 blocks of 64 cols. grid=512 -> 2 WG/CU.
// H LDS layout (bf16): elem (r,k) at r*1024 + (((k>>3)^(r&7))<<3) + (k&7)  [XOR swizzle]
__global__ __launch_bounds__(256) void recurrence_k(
    const float* __restrict__ xw1,            // [8192][1024]
    const float* __restrict__ w2,             // [2048][2048] f32
    const __hip_bfloat16* __restrict__ w2t,   // [1024][1024] bf16, [j][k] = w2[k][j]
    __hip_bfloat16* __restrict__ hidden) {    // [8192][1024]
  __shared__ __align__(16) __hip_bfloat16 H[16 * 1024];  // 32 KiB
  __shared__ __align__(16) float accL[16 * 68];          // [r][c], pad 68
  __shared__ __align__(16) float w2blk[64 * 64];         // [jj][c] f32, 16 KiB
  const int tid = threadIdx.x;
  const int l = tid & 63;
  const int w = tid >> 6;
  const int R0 = blockIdx.x * 16;
  const int rT = tid >> 4;  // solve row (0..15)
  const int g  = tid & 15;  // solve col group (4 cols each)
  const int q  = l >> 4;    // k-quarter within wave
  const int fr = l & 15;    // frag row/col within wave

  for (int b = 0; b < 16; ++b) {
    const int B0 = b * 64;
    // (A) stage in-block w2 [64][64] f32 via global_load_lds (linear dest)
#pragma unroll
    for (int i = 0; i < 4; ++i) {
      const int e = i * 1024 + tid * 4;
      const int jj = e >> 6, c = e & 63;
      gload_lds16(w2 + (size_t)(B0 + jj) * 2048 + (B0 + c), &w2blk[e]);
    }
    // (B) init C frag from xw1 (frag layout: row=q*4+j, col=fr)
    f32x4 cf;
    const int col = B0 + w * 16 + fr;
#pragma unroll
    for (int j = 0; j < 4; ++j)
      cf[j] = xw1[(size_t)(R0 + q * 4 + j) * 1024 + col];
    // (C) cross-block MFMA over previous columns, 1-deep prefetch
    if (B0 > 0) {
      int kr0 = q * 8;
      bf16x8 aqc = *(const bf16x8*)&H[fr * 1024 + (((kr0 >> 3) ^ (fr & 7)) << 3)];
      bf16x8 bqc = *(const bf16x8*)&w2t[(size_t)col * 1024 + kr0];
      for (int k0 = 0; k0 < B0; k0 += 32) {
        const int k1 = (k0 + 32 < B0) ? k0 + 32 : 0;  // clamp: dummy safe load
        const int kr = k1 + q * 8;
        bf16x8 aqn = *(const bf16x8*)&H[fr * 1024 + (((kr >> 3) ^ (fr & 7)) << 3)];
        bf16x8 bqn = *(const bf16x8*)&w2t[(size_t)col * 1024 + kr];
        cf = __builtin_amdgcn_mfma_f32_16x16x32_bf16(aqc, bqc, cf, 0, 0, 0);
        aqc = aqn; bqc = bqn;
      }
    }
    // (D) frag -> accL[r][c]
#pragma unroll
    for (int j = 0; j < 4; ++j)
      accL[(q * 4 + j) * 68 + w * 16 + fr] = cf[j];
    __syncthreads();  // (E) accL visible; w2blk gload drained (vmcnt)
    // (F) in-block solve, grouped by 4 cols. Thread owns row rT, cols g*4..g*4+3.
    f32x4 ac = *(const f32x4*)&accL[rT * 68 + g * 4];
#pragma unroll
    for (int jg = 0; jg < 16; ++jg) {
      const int j0 = jg * 4;
      const f32x4 wr0 = *(const f32x4*)&w2blk[(j0 + 0) * 64 + g * 4];
      const f32x4 wr1 = *(const f32x4*)&w2blk[(j0 + 1) * 64 + g * 4];
      const f32x4 wr2 = *(const f32x4*)&w2blk[(j0 + 2) * 64 + g * 4];
      const f32x4 wr3 = *(const f32x4*)&w2blk[(j0 + 3) * 64 + g * 4];
      // owner-local chain (valid where g==jg; computed on all lanes, cheap)
      const float h0 = fmaxf(ac[0], 0.f);
      const float a1 = ac[1] + h0 * wr0[1];
      const float h1 = fmaxf(a1, 0.f);
      const float a2 = ac[2] + h0 * wr0[2] + h1 * wr1[2];
      const float h2 = fmaxf(a2, 0.f);
      const float a3 = ac[3] + h0 * wr0[3] + h1 * wr1[3] + h2 * wr2[3];
      const float h3 = fmaxf(a3, 0.f);
      // broadcast owner's 4 h-values to the whole row-group
      const int src = (l & 48) | jg;
      const float b0 = __shfl(h0, src, 64);
      const float b1 = __shfl(h1, src, 64);
      const float b2 = __shfl(h2, src, 64);
      const float b3 = __shfl(h3, src, 64);
      if (g == jg) {
        // store 4 bf16 (8B, aligned: (j0&7) in {0,4}) into swizzled H
        const int k = B0 + j0;
        union { __hip_bfloat16 hh[4]; uint2 v; } u;
        u.hh[0] = __float2bfloat16(h0); u.hh[1] = __float2bfloat16(h1);
        u.hh[2] = __float2bfloat16(h2); u.hh[3] = __float2bfloat16(h3);
        *(uint2*)&H[rT * 1024 + (((k >> 3) ^ (rT & 7)) << 3) + (k & 7)] = u.v;
      } else if (g > jg) {
#pragma unroll
        for (int i = 0; i < 4; ++i)
          ac[i] += b0 * wr0[i] + b1 * wr1[i] + b2 * wr2[i] + b3 * wr3[i];
      }
    }
    __syncthreads();  // (G) H block visible to all
    // (H) copy this block's H to global hidden (16B per thread, 128 threads)
    if (tid < 128) {
      const int r5 = tid >> 3, seg = tid & 7;
      const int kk = B0 + seg * 8;
      const int gsw = (kk >> 3) ^ (r5 & 7);
      const i32x4 v = *(const i32x4*)&H[r5 * 1024 + gsw * 8];
      *(i32x4*)&hidden[(size_t)(R0 + r5) * 1024 + kk] = v;
    }
  }
}

extern "C" void kernel_launch(void* const* d_in, const int* in_sizes, int n_in,
                              void* d_out, int out_size, void* d_ws, size_t ws_size,
                              hipStream_t stream) {
  const float* x  = (const float*)d_in[0];
  const float* w1 = (const float*)d_in[1];
  const float* w2 = (const float*)d_in[2];
  const float* w3 = (const float*)d_in[3];
  const float* w4 = (const float*)d_in[4];
  const float* b1 = (const float*)d_in[5];
  const float* b2 = (const float*)d_in[6];
  float* out = (float*)d_out;

  char* ws = (char*)d_ws;
  size_t off = 0;
  auto alloc = [&](size_t bytes) {
    char* p = ws + off;
    off += (bytes + 255) & ~(size_t)255;
    return p;
  };
  __hip_bfloat16* x_bf = (__hip_bfloat16*)alloc(8192ull * 2048 * 2);
  float*          xw1  = (float*)alloc(8192ull * 1024 * 4);
  __hip_bfloat16* hid  = (__hip_bfloat16*)alloc(8192ull * 1024 * 2);
  __hip_bfloat16* w1t  = (__hip_bfloat16*)alloc(1024ull * 2048 * 2);
  __hip_bfloat16* w2t  = (__hip_bfloat16*)alloc(1024ull * 1024 * 2);
  __hip_bfloat16* w3t  = (__hip_bfloat16*)alloc(1024ull * 1024 * 2);
  __hip_bfloat16* w4t  = (__hip_bfloat16*)alloc(1024ull * 2048 * 2);

  cvt_bf16x8<<<dim3(8192), dim3(256), 0, stream>>>(x, x_bf, 8192L * 2048);

  dim3 tb(32, 8);
  transpose_cvt<<<dim3(64, 32), tb, 0, stream>>>(w1, w1t, 2048, 2048, 1024);
  transpose_cvt<<<dim3(32, 32), tb, 0, stream>>>(w2, w2t, 2048, 1024, 1024);
  transpose_cvt<<<dim3(32, 32), tb, 0, stream>>>(w3, w3t, 1000, 1024, 1000);
  transpose_cvt<<<dim3(64, 32), tb, 0, stream>>>(w4, w4t, 1000, 2048, 1000);

  // xw1 = x @ w1[:, :1024] + b1
  gemm_bf16_nt<1><<<dim3(64, 8), dim3(256), 0, stream>>>(
      x_bf, w1t, 2048, (const __hip_bfloat16*)nullptr, (const __hip_bfloat16*)nullptr, 0,
      b1, xw1, 1024, 1024);

  recurrence_k<<<dim3(512), dim3(256), 0, stream>>>(xw1, w2, w2t, hid);

  // out = hidden @ w3[:1024] + x @ w4 + b2
  gemm_bf16_nt<2><<<dim3(64, 8), dim3(256), 0, stream>>>(
      hid, w3t, 1024, x_bf, w4t, 2048, b2, out, 1000, 1000);

  (void)in_sizes; (void)n_in; (void)out_size; (void)ws_size;
}

// Round 3
// 429.754 us; speedup vs baseline: 1.1285x; 1.0031x over previous
//
#include <hip/hip_runtime.h>
#include <hip/hip_bf16.h>

// SDNN: xw1 = x@w1[:, :1024]+b1 ; h[:,j]=relu(xw1[:,j]+h@w2[:,j]) j<1024 ;
//       out = h@w3[:1024]+x@w4+b2.
// R2->R3: recurrence made RIGHT-looking: full acc row-panel lives in registers
//         (16 f32x4 frags/thread, wave-interleaved cols); after solving block b
//         its H tile updates all future frags via independent MFMAs (ILP hides
//         the w2t L2 latency that the left-looking chained version exposed).

typedef __bf16 bf16x8 __attribute__((ext_vector_type(8)));
typedef float f32x4 __attribute__((ext_vector_type(4)));
typedef int i32x4 __attribute__((ext_vector_type(4)));

__device__ __forceinline__ void gload_lds16(const void* gsrc, void* ldst) {
#if __has_builtin(__builtin_amdgcn_global_load_lds)
  void* g = const_cast<void*>(gsrc);
  __builtin_amdgcn_global_load_lds((__attribute__((address_space(1))) void*)g,
                                   (__attribute__((address_space(3))) void*)ldst,
                                   16, 0, 0);
#else
  *(i32x4*)ldst = *(const i32x4*)gsrc;
#endif
}

// ---------- converts ----------
__global__ __launch_bounds__(256) void cvt_bf16x8(const float* __restrict__ src,
                                                  __hip_bfloat16* __restrict__ dst,
                                                  long n) {
  long i = ((long)blockIdx.x * blockDim.x + threadIdx.x) * 8;
  if (i >= n) return;
  f32x4 a = *(const f32x4*)(src + i);
  f32x4 b = *(const f32x4*)(src + i + 4);
  union { __hip_bfloat16 h[8]; i32x4 v; } u;
#pragma unroll
  for (int j = 0; j < 4; ++j) {
    u.h[j]     = __float2bfloat16(a[j]);
    u.h[4 + j] = __float2bfloat16(b[j]);
  }
  *(i32x4*)(dst + i) = u.v;
}

// dst[j][k] = (j < Juse) ? bf16(src[k][j]) : 0 ; dst is [1024][Kuse]
__global__ __launch_bounds__(256) void transpose_cvt(const float* __restrict__ src,
                                                     __hip_bfloat16* __restrict__ dst,
                                                     int srcStride, int Kuse, int Juse) {
  __shared__ float tile[32][33];
  const int k0 = blockIdx.x * 32, j0 = blockIdx.y * 32;
  const int tx = threadIdx.x, ty = threadIdx.y;  // 32 x 8
#pragma unroll
  for (int i = 0; i < 4; ++i) {
    const int k = k0 + ty + i * 8, j = j0 + tx;
    tile[ty + i * 8][tx] = (j < Juse) ? src[(size_t)k * srcStride + j] : 0.f;
  }
  __syncthreads();
#pragma unroll
  for (int i = 0; i < 4; ++i) {
    const int j = j0 + ty + i * 8, k = k0 + tx;
    dst[(size_t)j * Kuse + k] = __float2bfloat16(tile[tx][ty + i * 8]);
  }
}

// ---------- bf16 MFMA GEMM, C = sum_p A_p @ B_p^T + bias (m97 structure) ----------
// A: [M][K] bf16 row-major ; Bt: [N][K] bf16 row-major ; C: [M][Cstride] f32
template <int NP>
__global__ __launch_bounds__(256) void gemm_bf16_nt(
    const __hip_bfloat16* __restrict__ A0, const __hip_bfloat16* __restrict__ B0t, int K0,
    const __hip_bfloat16* __restrict__ A1, const __hip_bfloat16* __restrict__ B1t, int K1,
    const float* __restrict__ bias, float* __restrict__ C, int Cstride, int Nvalid) {
  __shared__ __align__(16) __hip_bfloat16 As[128 * 64];
  __shared__ __align__(16) __hip_bfloat16 Bs[128 * 64];
  const int tid = threadIdx.x;
  const int l = tid & 63;
  const int w = tid >> 6;
  const int wr = w >> 1, wc = w & 1;
  const int bm = blockIdx.x * 128;
  const int bn = blockIdx.y * 128;

  f32x4 acc[4][4] = {};

#pragma unroll
  for (int p = 0; p < NP; ++p) {
    const __hip_bfloat16* A  = (p == 0) ? A0 : A1;
    const __hip_bfloat16* Bt = (p == 0) ? B0t : B1t;
    const int K = (p == 0) ? K0 : K1;
    for (int kt = 0; kt < K; kt += 64) {
      __syncthreads();
      const int srow = tid >> 3;
      const int sk = (tid & 7) * 8;
#pragma unroll
      for (int i = 0; i < 4; ++i) {
        gload_lds16(A  + (size_t)(bm + i * 32 + srow) * K + kt + sk,
                    &As[(i * 32 + srow) * 64 + sk]);
        gload_lds16(Bt + (size_t)(bn + i * 32 + srow) * K + kt + sk,
                    &Bs[(i * 32 + srow) * 64 + sk]);
      }
      __syncthreads();
#pragma unroll
      for (int kk = 0; kk < 64; kk += 32) {
        const int ko = kk + (l >> 4) * 8;
        bf16x8 aq[4], bq[4];
#pragma unroll
        for (int m = 0; m < 4; ++m)
          aq[m] = *(const bf16x8*)&As[(wr * 64 + m * 16 + (l & 15)) * 64 + ko];
#pragma unroll
        for (int n = 0; n < 4; ++n)
          bq[n] = *(const bf16x8*)&Bs[(wc * 64 + n * 16 + (l & 15)) * 64 + ko];
#pragma unroll
        for (int m = 0; m < 4; ++m)
#pragma unroll
          for (int n = 0; n < 4; ++n)
            acc[m][n] = __builtin_amdgcn_mfma_f32_16x16x32_bf16(aq[m], bq[n], acc[m][n], 0, 0, 0);
      }
    }
  }
#pragma unroll
  for (int m = 0; m < 4; ++m) {
    const int row0 = bm + wr * 64 + m * 16 + (l >> 4) * 4;
#pragma unroll
    for (int n = 0; n < 4; ++n) {
      const int col = bn + wc * 64 + n * 16 + (l & 15);
      if (col < Nvalid) {
        const float bv = bias[col];
#pragma unroll
        for (int j = 0; j < 4; ++j)
          C[(size_t)(row0 + j) * Cstride + col] = acc[m][n][j] + bv;
      }
    }
  }
}

// ---------- recurrence (v3, right-looking) ----------
// Per WG: 16 rows, 16 blocks of 64 cols, grid=512.
// Acc panel [16 rows x 1024 cols] in registers: wave w, frag f covers cols
// (f*4+w)*16 + fr (interleaved -> per-block MFMA work balanced across waves),
// rows q*4+j.  After solving block b, H tile updates frags f>b (independent
// MFMAs -> w2t L2 latency hidden by ILP instead of exposed on a chain).
// H LDS layout (bf16): elem (r,k) at r*1024 + (((k>>3)^(r&7))<<3) + (k&7)
__global__ __launch_bounds__(256) void recurrence_k(
    const float* __restrict__ xw1,            // [8192][1024]
    const float* __restrict__ w2,             // [2048][2048] f32
    const __hip_bfloat16* __restrict__ w2t,   // [1024][1024] bf16, [j][k] = w2[k][j]
    __hip_bfloat16* __restrict__ hidden) {    // [8192][1024]
  __shared__ __align__(16) __hip_bfloat16 H[16 * 1024];  // 32 KiB
  __shared__ __align__(16) float accS[16 * 68];          // [r][c], pad 68
  __shared__ __align__(16) float w2blk[64 * 64];         // [jj][c] f32, 16 KiB
  const int tid = threadIdx.x;
  const int l = tid & 63;
  const int w = tid >> 6;
  const int R0 = blockIdx.x * 16;
  const int rT = tid >> 4;  // solve row (0..15)
  const int g  = tid & 15;  // solve col group (4 cols each)
  const int q  = l >> 4;    // frag row-quarter
  const int fr = l & 15;    // frag col within 16

  // init acc panel from xw1 (frag layout: row=q*4+j, col=fr)
  f32x4 af[16];
#pragma unroll
  for (int f = 0; f < 16; ++f) {
    const int c = (f * 4 + w) * 16 + fr;
#pragma unroll
    for (int j = 0; j < 4; ++j)
      af[f][j] = xw1[(size_t)(R0 + q * 4 + j) * 1024 + c];
  }

  for (int b = 0; b < 16; ++b) {
    const int B0 = b * 64;
    // (A) stage in-block w2 [64][64] f32 via global_load_lds (linear dest)
#pragma unroll
    for (int i = 0; i < 4; ++i) {
      const int e = i * 1024 + tid * 4;
      const int jj = e >> 6, c = e & 63;
      gload_lds16(w2 + (size_t)(B0 + jj) * 2048 + (B0 + c), &w2blk[e]);
    }
    // (B) extract frag b -> accS[r][c]  (cols of frag b are exactly B0+w*16+fr)
#pragma unroll
    for (int f = 0; f < 16; ++f)
      if (f == b) {
#pragma unroll
        for (int j = 0; j < 4; ++j)
          accS[(q * 4 + j) * 68 + w * 16 + fr] = af[f][j];
      }
    __syncthreads();  // accS visible; w2blk gload drained
    // (C) in-block solve, grouped by 4 cols. Thread owns row rT, cols g*4..+3.
    f32x4 ac = *(const f32x4*)&accS[rT * 68 + g * 4];
#pragma unroll
    for (int jg = 0; jg < 16; ++jg) {
      const int j0 = jg * 4;
      const f32x4 wr0 = *(const f32x4*)&w2blk[(j0 + 0) * 64 + g * 4];
      const f32x4 wr1 = *(const f32x4*)&w2blk[(j0 + 1) * 64 + g * 4];
      const f32x4 wr2 = *(const f32x4*)&w2blk[(j0 + 2) * 64 + g * 4];
      const f32x4 wr3 = *(const f32x4*)&w2blk[(j0 + 3) * 64 + g * 4];
      // owner-local chain (valid where g==jg; computed on all lanes, cheap)
      const float h0 = fmaxf(ac[0], 0.f);
      const float a1 = ac[1] + h0 * wr0[1];
      const float h1 = fmaxf(a1, 0.f);
      const float a2 = ac[2] + h0 * wr0[2] + h1 * wr1[2];
      const float h2 = fmaxf(a2, 0.f);
      const float a3 = ac[3] + h0 * wr0[3] + h1 * wr1[3] + h2 * wr2[3];
      const float h3 = fmaxf(a3, 0.f);
      // broadcast owner's 4 h-values to the whole row-group
      const int src = (l & 48) | jg;
      const float b0 = __shfl(h0, src, 64);
      const float b1 = __shfl(h1, src, 64);
      const float b2 = __shfl(h2, src, 64);
      const float b3 = __shfl(h3, src, 64);
      if (g == jg) {
        const int k = B0 + j0;
        union { __hip_bfloat16 hh[4]; uint2 v; } u;
        u.hh[0] = __float2bfloat16(h0); u.hh[1] = __float2bfloat16(h1);
        u.hh[2] = __float2bfloat16(h2); u.hh[3] = __float2bfloat16(h3);
        *(uint2*)&H[rT * 1024 + (((k >> 3) ^ (rT & 7)) << 3) + (k & 7)] = u.v;
      } else if (g > jg) {
#pragma unroll
        for (int i = 0; i < 4; ++i)
          ac[i] += b0 * wr0[i] + b1 * wr1[i] + b2 * wr2[i] + b3 * wr3[i];
      }
    }
    __syncthreads();  // (D) H block visible to all
    // (E) copy this block's H to global hidden (16B per thread, 128 threads)
    if (tid < 128) {
      const int r5 = tid >> 3, seg = tid & 7;
      const int kk = B0 + seg * 8;
      const int gsw = (kk >> 3) ^ (r5 & 7);
      const i32x4 v = *(const i32x4*)&H[r5 * 1024 + gsw * 8];
      *(i32x4*)&hidden[(size_t)(R0 + r5) * 1024 + kk] = v;
    }
    // (F) right-looking update: frags f>b get H_blk @ w2t (independent MFMAs)
#pragma unroll
    for (int f = 0; f < 16; ++f)
      if (f > b) {
        const int c = (f * 4 + w) * 16 + fr;
#pragma unroll
        for (int kk = 0; kk < 64; kk += 32) {
          const int kr = B0 + kk + q * 8;
          const bf16x8 aq = *(const bf16x8*)&H[fr * 1024 + (((kr >> 3) ^ (fr & 7)) << 3)];
          const bf16x8 bq = *(const bf16x8*)&w2t[(size_t)c * 1024 + kr];
          af[f] = __builtin_amdgcn_mfma_f32_16x16x32_bf16(aq, bq, af[f], 0, 0, 0);
        }
      }
  }
}

extern "C" void kernel_launch(void* const* d_in, const int* in_sizes, int n_in,
                              void* d_out, int out_size, void* d_ws, size_t ws_size,
                              hipStream_t stream) {
  const float* x  = (const float*)d_in[0];
  const float* w1 = (const float*)d_in[1];
  const float* w2 = (const float*)d_in[2];
  const float* w3 = (const float*)d_in[3];
  const float* w4 = (const float*)d_in[4];
  const float* b1 = (const float*)d_in[5];
  const float* b2 = (const float*)d_in[6];
  float* out = (float*)d_out;

  char* ws = (char*)d_ws;
  size_t off = 0;
  auto alloc = [&](size_t bytes) {
    char* p = ws + off;
    off += (bytes + 255) & ~(size_t)255;
    return p;
  };
  __hip_bfloat16* x_bf = (__hip_bfloat16*)alloc(8192ull * 2048 * 2);
  float*          xw1  = (float*)alloc(8192ull * 1024 * 4);
  __hip_bfloat16* hid  = (__hip_bfloat16*)alloc(8192ull * 1024 * 2);
  __hip_bfloat16* w1t  = (__hip_bfloat16*)alloc(1024ull * 2048 * 2);
  __hip_bfloat16* w2t  = (__hip_bfloat16*)alloc(1024ull * 1024 * 2);
  __hip_bfloat16* w3t  = (__hip_bfloat16*)alloc(1024ull * 1024 * 2);
  __hip_bfloat16* w4t  = (__hip_bfloat16*)alloc(1024ull * 2048 * 2);

  cvt_bf16x8<<<dim3(8192), dim3(256), 0, stream>>>(x, x_bf, 8192L * 2048);

  dim3 tb(32, 8);
  transpose_cvt<<<dim3(64, 32), tb, 0, stream>>>(w1, w1t, 2048, 2048, 1024);
  transpose_cvt<<<dim3(32, 32), tb, 0, stream>>>(w2, w2t, 2048, 1024, 1024);
  transpose_cvt<<<dim3(32, 32), tb, 0, stream>>>(w3, w3t, 1000, 1024, 1000);
  transpose_cvt<<<dim3(64, 32), tb, 0, stream>>>(w4, w4t, 1000, 2048, 1000);

  // xw1 = x @ w1[:, :1024] + b1
  gemm_bf16_nt<1><<<dim3(64, 8), dim3(256), 0, stream>>>(
      x_bf, w1t, 2048, (const __hip_bfloat16*)nullptr, (const __hip_bfloat16*)nullptr, 0,
      b1, xw1, 1024, 1024);

  recurrence_k<<<dim3(512), dim3(256), 0, stream>>>(xw1, w2, w2t, hid);

  // out = hidden @ w3[:1024] + x @ w4 + b2
  gemm_bf16_nt<2><<<dim3(64, 8), dim3(256), 0, stream>>>(
      hid, w3t, 1024, x_bf, w4t, 2048, b2, out, 1000, 1000);

  (void)in_sizes; (void)n_in; (void)out_size; (void)ws_size;
}